// Round 5
// baseline (838.278 us; speedup 1.0000x reference)
//
#include <hip/hip_runtime.h>

#define NF 64
#define NH 32
#define NK 16
#define BLOCK 512
#define NWAVES (BLOCK / 64)

// LDS: permL 2048 B + sortL 256 B = 2.3 KB -> occupancy is VGPR-bound.
// Weights are NOT staged: after the per-wave distinct-node loop below, all
// weight pointers are wave-uniform (readfirstlane) -> compiler emits s_load,
// FMAs take the weight as an SGPR operand (1 sgpr src is legal per VOP).

__global__ __attribute__((amdgpu_flat_work_group_size(BLOCK, BLOCK),
                          amdgpu_waves_per_eu(4, 8)))
void tree_mlp_kernel(
    const float* __restrict__ x,
    const float* __restrict__ W1, const float* __restrict__ b1,
    const float* __restrict__ W2, const float* __restrict__ b2,
    const float* __restrict__ W3, const float* __restrict__ b3,
    const float* __restrict__ leaf_best, const int* __restrict__ subset_idx,
    float* __restrict__ out, int N)
{
    __shared__ unsigned permL[BLOCK];   // 2048 B
    __shared__ int      sortL[64];      // 256 B  (nb*NWAVES <= 64)

    const int tid  = threadIdx.x;
    const int lane = tid & 63;
    const int wv   = tid >> 6;

    const int s = blockIdx.x * BLOCK + tid;
    int valid = (s < N) ? 1 : 0;
    int id    = valid ? s : 0;          // invalid lanes shadow sample 0, stay live
    int loc = 0, off = 0;

    #pragma unroll 1                    // keep level loop rolled (I$)
    for (int level = 0; level < 4; ++level) {
        if (level > 0) {
            // ---- in-block counting sort by loc (ballot-based) ----
            const int nb = 1 << level;
            int myrank = 0;
            #pragma unroll 1
            for (int b = 0; b < nb; ++b) {
                const unsigned long long m = __ballot(loc == b);
                if (loc == b)
                    myrank = __popcll(m & ((1ull << lane) - 1ull));
                if (lane == 0)
                    sortL[b * NWAVES + wv] = (int)__popcll(m);
            }
            __syncthreads();
            // wave-parallel exclusive prefix (replaces R4's serial tid==0 loop)
            if (wv == 0) {
                const int mcnt = nb * NWAVES;
                const int cnt = (lane < mcnt) ? sortL[lane] : 0;
                int v = cnt;
                #pragma unroll
                for (int d = 1; d < 64; d <<= 1) {
                    const int t = __shfl_up(v, d);
                    if (lane >= d) v += t;
                }
                if (lane < mcnt) sortL[lane] = v - cnt;
            }
            __syncthreads();
            const int slot = sortL[loc * NWAVES + wv] + myrank;
            permL[slot] = ((unsigned)id << 5) | ((unsigned)valid << 4) | (unsigned)loc;
            __syncthreads();
            const unsigned p = permL[tid];
            id    = (int)(p >> 5);
            valid = (int)((p >> 4) & 1u);
            loc   = (int)(p & 15u);
            // no barrier needed: next level's LDS writes are >=2 barriers away
        }

        const int node = off + loc;     // ~wave-uniform after sort
        int bit = 0;

        // ---- uniform loop over distinct nodes present in this wave ----
        unsigned long long rem = ~0ull;
        #pragma unroll 1
        while (rem) {
            const int lead = (int)__ffsll((long long)rem) - 1;
            const int n0 = __builtin_amdgcn_readfirstlane(__shfl(node, lead));
            const bool mine = (node == n0);

            // subset indices: uniform -> SGPRs; gather x per lane
            const int* __restrict__ si = subset_idx + n0 * NK;
            const float* __restrict__ xr = x + (size_t)id * NF;
            float xs[NK];
            #pragma unroll
            for (int k = 0; k < NK; ++k) xs[k] = xr[si[k]];

            // h1 = leaky(W1[n0] @ xs + b1[n0])   (weights via scalar loads)
            const float* __restrict__ w1 = W1 + n0 * (NH * NK);
            const float* __restrict__ bb1 = b1 + n0 * NH;
            float h1v[NH];
            #pragma unroll
            for (int j = 0; j < NH; ++j) {
                float acc = bb1[j];
                #pragma unroll
                for (int k = 0; k < NK; ++k) acc += w1[j * NK + k] * xs[k];
                // max(x, 0.01x) == (x>=0 ? x : 0.01x) exactly (incl. -0)
                h1v[j] = fmaxf(acc, 0.01f * acc);
            }

            // h2 = leaky(W2[n0] @ h1 + b2[n0])
            const float* __restrict__ w2 = W2 + n0 * (NH * NH);
            const float* __restrict__ bb2 = b2 + n0 * NH;
            float h2v[NH];
            #pragma unroll
            for (int g = 0; g < NH; ++g) {
                float acc = bb2[g];
                #pragma unroll
                for (int h = 0; h < NH; ++h) acc += w2[g * NH + h] * h1v[h];
                h2v[g] = fmaxf(acc, 0.01f * acc);
            }

            // logits; p0 < 0.5  <=>  l0 < l1 (softmax monotone)
            const float* __restrict__ w3 = W3 + n0 * (2 * NH);
            float l0 = b3[n0 * 2 + 0];
            float l1 = b3[n0 * 2 + 1];
            #pragma unroll
            for (int h = 0; h < NH; ++h) {
                l0 += w3[h]      * h2v[h];
                l1 += w3[NH + h] * h2v[h];
            }

            if (mine) bit = (l0 < l1) ? 1 : 0;
            rem &= ~__ballot(mine);
        }

        loc = 2 * loc + bit;
        off = 2 * off + 1;              // node offsets: 0, 1, 3, 7
    }

    if (valid) out[id] = leaf_best[loc];
}

extern "C" void kernel_launch(void* const* d_in, const int* in_sizes, int n_in,
                              void* d_out, int out_size, void* d_ws, size_t ws_size,
                              hipStream_t stream) {
    const float* x         = (const float*)d_in[0];
    const float* W1        = (const float*)d_in[1];
    const float* b1        = (const float*)d_in[2];
    const float* W2        = (const float*)d_in[3];
    const float* b2        = (const float*)d_in[4];
    const float* W3        = (const float*)d_in[5];
    const float* b3        = (const float*)d_in[6];
    const float* leaf_best = (const float*)d_in[7];
    const int*   subset    = (const int*)d_in[8];

    const int N = in_sizes[0] / NF;
    const int grid = (N + BLOCK - 1) / BLOCK;
    tree_mlp_kernel<<<grid, BLOCK, 0, stream>>>(
        x, W1, b1, W2, b2, W3, b3, leaf_best, subset, (float*)d_out, N);
}